// Round 3
// baseline (484.765 us; speedup 1.0000x reference)
//
#include <hip/hip_runtime.h>
#include <math.h>

#define NHEAD 16
#define TSEQ  2048
#define BATCH 2
#define DM    2048

typedef __attribute__((ext_vector_type(8))) short bf16x8;
typedef __attribute__((ext_vector_type(4))) float f32x4;

__device__ __forceinline__ short f2bf(float f) {
    unsigned u = __builtin_bit_cast(unsigned, f);
    u += 0x7fff + ((u >> 16) & 1);          // RNE
    return (short)(u >> 16);
}
__device__ __forceinline__ float bf2f(short s) {
    unsigned u = ((unsigned)(unsigned short)s) << 16;
    return __builtin_bit_cast(float, u);
}
__device__ __forceinline__ void gload_lds16(const void* g, void* l) {
    __builtin_amdgcn_global_load_lds(
        (const __attribute__((address_space(1))) unsigned int*)g,
        (__attribute__((address_space(3))) unsigned int*)l, 16, 0, 0);
}

// ---------------------------------------------------------------------------
// merged fp32->bf16 casts: x (8.39M), w_qkv (12.58M), w_out (4.19M)
// ---------------------------------------------------------------------------
__global__ __launch_bounds__(256)
void cast_all(const float* __restrict__ x, short* __restrict__ xb,
              const float* __restrict__ wq, short* __restrict__ wqb,
              const float* __restrict__ wo, short* __restrict__ wob)
{
    int bid = blockIdx.x;
    const float* src; short* dst; int lb;
    if (bid < 4096)       { src = x;  dst = xb;  lb = bid; }
    else if (bid < 10240) { src = wq; dst = wqb; lb = bid - 4096; }
    else                  { src = wo; dst = wob; lb = bid - 10240; }
    int i = (lb * 256 + threadIdx.x) * 8;
    float4 a = *(const float4*)(src + i);
    float4 b = *(const float4*)(src + i + 4);
    bf16x8 o;
    o[0]=f2bf(a.x); o[1]=f2bf(a.y); o[2]=f2bf(a.z); o[3]=f2bf(a.w);
    o[4]=f2bf(b.x); o[5]=f2bf(b.y); o[6]=f2bf(b.z); o[7]=f2bf(b.w);
    *(bf16x8*)(dst + i) = o;
}

// ---------------------------------------------------------------------------
// QKV GEMM: 256x256 tile, BK=64, 8 waves (2Mx4N), 8-phase schedule with
// counted vmcnt (T3+T4), setprio around MFMA clusters (T5), chunk-XOR LDS
// swizzle (T2). Fused bias + RoPE + fragment repack epilogue.
// qfrag/kfrag: [bh][t16][kc4][lane64][8]   (A-operand layout)
// vfrag:       [bh][kb64][dt8][kc2][lane64][8] (V^T A-operand layout)
// ---------------------------------------------------------------------------
#define BARRIER() __builtin_amdgcn_s_barrier()
#define WAIT_LGKM0() do { asm volatile("s_waitcnt lgkmcnt(0)" ::: "memory"); \
                          __builtin_amdgcn_sched_barrier(0); } while (0)
#define WAIT_VM(N) asm volatile("s_waitcnt vmcnt(" #N ")" ::: "memory")

#define LOAD_A(BUF, MH) do {                                                  \
    const short* base_ = sm + (BUF)*32768 + (MH)*8192;                        \
    _Pragma("unroll")                                                         \
    for (int m_ = 0; m_ < 4; ++m_) {                                          \
        int j_ = wr*64 + m_*16 + lane15;                                      \
        const short* rp_ = base_ + j_*64;                                     \
        int sw_ = (j_ & 7) << 3;                                              \
        af[m_][0] = *(const bf16x8*)(rp_ + ((quad << 3) ^ sw_));              \
        af[m_][1] = *(const bf16x8*)(rp_ + ((32 + (quad << 3)) ^ sw_));       \
    }                                                                         \
} while (0)

#define LOAD_B(BUF, NH, BB) do {                                              \
    const short* base_ = sm + (BUF)*32768 + 16384 + (NH)*8192;                \
    _Pragma("unroll")                                                         \
    for (int n_ = 0; n_ < 2; ++n_) {                                          \
        int j_ = wc*32 + n_*16 + lane15;                                      \
        const short* rp_ = base_ + j_*64;                                     \
        int sw_ = (j_ & 7) << 3;                                              \
        BB[n_][0] = *(const bf16x8*)(rp_ + ((quad << 3) ^ sw_));              \
        BB[n_][1] = *(const bf16x8*)(rp_ + ((32 + (quad << 3)) ^ sw_));       \
    }                                                                         \
} while (0)

#define STAGE_A(T, MH) do { if ((T) < 32) {                                   \
    short* dst_ = sm + (((T) & 1) << 15) + ((MH) << 13);                      \
    const int kt_ = (T) << 6;                                                 \
    _Pragma("unroll")                                                         \
    for (int i_ = 0; i_ < 2; ++i_) {                                          \
        int ci_ = i_*512 + tid;                                               \
        int j_ = ci_ >> 3, lc_ = ci_ & 7;                                     \
        int r_ = (j_ & 63) + ((j_ >> 6) << 7) + (MH)*64;                      \
        gload_lds16(A + (size_t)(row0 + r_)*2048 + kt_ + ((lc_ ^ (j_ & 7)) << 3), \
                    dst_ + ci_*8);                                            \
    } } } while (0)

#define STAGE_B(T, NH) do { if ((T) < 32) {                                   \
    short* dst_ = sm + (((T) & 1) << 15) + 16384 + ((NH) << 13);              \
    const int kt_ = (T) << 6;                                                 \
    _Pragma("unroll")                                                         \
    for (int i_ = 0; i_ < 2; ++i_) {                                          \
        int ci_ = i_*512 + tid;                                               \
        int j_ = ci_ >> 3, lc_ = ci_ & 7;                                     \
        int r_ = (j_ & 31) + ((j_ >> 5) << 6) + (NH)*32;                      \
        gload_lds16(W + (size_t)(col0 + r_)*2048 + kt_ + ((lc_ ^ (j_ & 7)) << 3), \
                    dst_ + ci_*8);                                            \
    } } } while (0)

#define MMA_Q(MH, NH, BB) do {                                                \
    _Pragma("unroll")                                                         \
    for (int m_ = 0; m_ < 4; ++m_) {                                          \
        _Pragma("unroll")                                                     \
        for (int n_ = 0; n_ < 2; ++n_) {                                      \
            f32x4 c_ = acc[(MH)*4 + m_][(NH)*2 + n_];                         \
            c_ = __builtin_amdgcn_mfma_f32_16x16x32_bf16(af[m_][0], BB[n_][0], c_, 0, 0, 0); \
            c_ = __builtin_amdgcn_mfma_f32_16x16x32_bf16(af[m_][1], BB[n_][1], c_, 0, 0, 0); \
            acc[(MH)*4 + m_][(NH)*2 + n_] = c_;                               \
        }                                                                     \
    }                                                                         \
} while (0)

__global__ __launch_bounds__(512, 2)
void gemm_qkv_rope(const short* __restrict__ A, const short* __restrict__ W,
                   const float* __restrict__ bias, short* __restrict__ qfrag,
                   short* __restrict__ kfrag, short* __restrict__ vfrag)
{
    __shared__ short sm[65536];                  // 128 KiB: 2 buf x (A 32K | B 32K)
    const int tid = threadIdx.x;
    const int lane = tid & 63, w = tid >> 6;
    const int lane15 = lane & 15, quad = lane >> 4;
    const int wr = w >> 2, wc = w & 3;           // 2M x 4N waves
    const int row0 = blockIdx.y * 256, col0 = blockIdx.x * 256;

    f32x4 acc[8][4];
    #pragma unroll
    for (int mi = 0; mi < 8; ++mi)
        #pragma unroll
        for (int ni = 0; ni < 4; ++ni)
            acc[mi][ni] = (f32x4){0.f, 0.f, 0.f, 0.f};

    bf16x8 af[4][2], bb0[2][2], bb1[2][2];

    // prologue: stage tiles 0 and 1 fully (16 loads/wave), keep tile1 in flight
    STAGE_A(0, 0); STAGE_B(0, 0); STAGE_A(0, 1); STAGE_B(0, 1);
    STAGE_A(1, 0); STAGE_B(1, 0); STAGE_A(1, 1); STAGE_B(1, 1);
    WAIT_VM(8);                                  // tile0 complete, tile1 in flight
    BARRIER();

    for (int i = 0; i < 16; ++i) {
        const int ta = 2*i + 2;                  // -> buf0
        const int tb = 2*i + 3;                  // -> buf1
        // ---- p1: Q(0,0) on buf0
        LOAD_A(0, 0);
        LOAD_B(0, 0, bb0);
        BARRIER(); WAIT_LGKM0();
        __builtin_amdgcn_s_setprio(1); MMA_Q(0, 0, bb0); __builtin_amdgcn_s_setprio(0);
        BARRIER();
        // ---- p2: Q(0,1)   (A'0/B'0 slots of buf0 now dead -> stage ta)
        LOAD_B(0, 1, bb1);
        STAGE_A(ta, 0); STAGE_B(ta, 0);
        BARRIER(); WAIT_LGKM0();
        __builtin_amdgcn_s_setprio(1); MMA_Q(0, 1, bb1); __builtin_amdgcn_s_setprio(0);
        BARRIER();
        // ---- p3: Q(1,1)   (B'1 slot dead)
        LOAD_A(0, 1);
        STAGE_B(ta, 1);
        BARRIER(); WAIT_LGKM0();
        __builtin_amdgcn_s_setprio(1); MMA_Q(1, 1, bb1); __builtin_amdgcn_s_setprio(0);
        BARRIER();
        // ---- p4: Q(1,0)   (A'1 slot dead); counted wait: tile t1 must be done
        STAGE_A(ta, 1);
        if (i == 15) { WAIT_VM(0); } else { WAIT_VM(8); }
        BARRIER();
        __builtin_amdgcn_s_setprio(1); MMA_Q(1, 0, bb0); __builtin_amdgcn_s_setprio(0);
        BARRIER();
        // ---- p5: Q(0,0) on buf1
        LOAD_A(1, 0);
        LOAD_B(1, 0, bb0);
        BARRIER(); WAIT_LGKM0();
        __builtin_amdgcn_s_setprio(1); MMA_Q(0, 0, bb0); __builtin_amdgcn_s_setprio(0);
        BARRIER();
        // ---- p6: Q(0,1)
        LOAD_B(1, 1, bb1);
        STAGE_A(tb, 0); STAGE_B(tb, 0);
        BARRIER(); WAIT_LGKM0();
        __builtin_amdgcn_s_setprio(1); MMA_Q(0, 1, bb1); __builtin_amdgcn_s_setprio(0);
        BARRIER();
        // ---- p7: Q(1,1)
        LOAD_A(1, 1);
        STAGE_B(tb, 1);
        BARRIER(); WAIT_LGKM0();
        __builtin_amdgcn_s_setprio(1); MMA_Q(1, 1, bb1); __builtin_amdgcn_s_setprio(0);
        BARRIER();
        // ---- p8: Q(1,0); counted wait: tile ta must be done for next p1
        STAGE_A(tb, 1);
        if (i < 15) { WAIT_VM(8); }
        BARRIER();
        __builtin_amdgcn_s_setprio(1); MMA_Q(1, 0, bb0); __builtin_amdgcn_s_setprio(0);
        BARRIER();
    }

    // ---- epilogue: two 128-col halves, each one type of one head ----
    const int b = row0 >> 11;
    const int t0g = row0 & 2047;
    #pragma unroll
    for (int ch = 0; ch < 2; ++ch) {
        const int cidx = (col0 >> 7) + ch;       // global 128-col index
        const int head = cidx / 3, type = cidx % 3;   // 0=q 1=k 2=v
        __syncthreads();                         // prev readers done / drain
        if ((wc >> 1) == ch) {                   // waves owning these cols
            #pragma unroll
            for (int ni = 0; ni < 4; ++ni) {
                int d = (wc & 1)*64 + ni*16 + lane15;
                float bv = bias[col0 + ch*128 + d];
                #pragma unroll
                for (int mi = 0; mi < 8; ++mi) {
                    int rowb = wr*128 + mi*16 + quad*4;
                    #pragma unroll
                    for (int r = 0; r < 4; ++r)
                        sm[(rowb + r)*136 + d] = f2bf(acc[mi][ni][r] + bv);
                }
            }
        }
        __syncthreads();
        if (type < 2) {   // q or k: rope + frag store (256 rows x 128 cols)
            const float sc = (type == 0) ? 0.022097086912079608f : 1.0f;
            short* dst = (type == 0 ? qfrag : kfrag) + (size_t)(b*NHEAD + head)*262144;
            #pragma unroll
            for (int it = 0; it < 4; ++it) {
                int c = it*512 + tid;
                int l15 = c & 15, q_ = (c >> 4) & 3, kc = (c >> 6) & 1, rowhi = c >> 7;
                int lrow = rowhi*16 + l15;
                int t = t0g + lrow;
                bf16x8 a8 = *(const bf16x8*)(sm + lrow*136 + kc*32 + q_*8);
                bf16x8 b8 = *(const bf16x8*)(sm + lrow*136 + kc*32 + q_*8 + 64);
                bf16x8 oa, ob;
                #pragma unroll
                for (int j = 0; j < 8; ++j) {
                    int d = kc*32 + q_*8 + j;
                    // theta_rev = 10000^(-d/64) / (2*pi)
                    float trev = exp2f(-(float)d * (13.287712379549449f / 64.0f))
                                 * 0.15915494309189535f;
                    float ang = (float)t * trev;
                    float fr = ang - floorf(ang);
                    float sn, cs;
                    __sincosf(fr * 6.283185307179586f, &sn, &cs);
                    float va = bf2f(a8[j]), vb = bf2f(b8[j]);
                    oa[j] = f2bf((va*cs - vb*sn)*sc);
                    ob[j] = f2bf((va*sn + vb*cs)*sc);
                }
                size_t base = (size_t)((t0g >> 4) + rowhi)*2048 + (q_*16 + l15)*8;
                *(bf16x8*)(dst + base + kc*512)        = oa;
                *(bf16x8*)(dst + base + kc*512 + 1024) = ob;
            }
        } else {          // v: transpose to vfrag (256 rows)
            short* dst = vfrag + (size_t)(b*NHEAD + head)*262144;
            #pragma unroll
            for (int it = 0; it < 8; ++it) {
                int c = it*512 + tid;
                int lane_ = c & 63, rest = c >> 6;
                int q_ = lane_ >> 4, l15 = lane_ & 15;
                int dt = rest & 7, kc2 = (rest >> 3) & 1, kbt = rest >> 4;
                int d = dt*16 + l15;
                bf16x8 v;
                #pragma unroll
                for (int j = 0; j < 8; ++j)
                    v[j] = sm[(kbt*64 + kc2*32 + q_*8 + j)*136 + d];
                *(bf16x8*)(dst + (size_t)((t0g >> 6) + kbt)*8192
                            + dt*1024 + kc2*512 + lane_*8) = v;
            }
        }
    }
}

// ---------------------------------------------------------------------------
// bf16 MFMA GEMM (NT) for out-projection (unchanged, fp32 out).
// ---------------------------------------------------------------------------
__global__ __launch_bounds__(256)
void gemm_out(const short* __restrict__ A, const short* __restrict__ W,
              const float* __restrict__ bias, float* __restrict__ Cout,
              int N, int K)
{
    __shared__ short As[128 * 64];
    __shared__ short Bs[128 * 64];
    const int tid = threadIdx.x;
    const int lane = tid & 63, w = tid >> 6;
    const int lane15 = lane & 15, quad = lane >> 4;
    const int wr = w >> 1, wc = w & 1;
    const int row0 = blockIdx.y * 128, col0 = blockIdx.x * 128;

    f32x4 acc[4][4];
    #pragma unroll
    for (int mi = 0; mi < 4; ++mi)
        #pragma unroll
        for (int ni = 0; ni < 4; ++ni)
            acc[mi][ni] = (f32x4){0.f, 0.f, 0.f, 0.f};

    for (int kt = 0; kt < K; kt += 64) {
        __syncthreads();
        #pragma unroll
        for (int i = 0; i < 4; ++i) {
            int ci = i * 256 + tid;
            int row = ci >> 3, lc = ci & 7;
            int gc = lc ^ (row & 7);
            gload_lds16(A + (size_t)(row0 + row) * K + kt + gc * 8, As + ci * 8);
            gload_lds16(W + (size_t)(col0 + row) * K + kt + gc * 8, Bs + ci * 8);
        }
        __syncthreads();
        #pragma unroll
        for (int kc = 0; kc < 2; ++kc) {
            bf16x8 af[4], bfr[4];
            #pragma unroll
            for (int mi = 0; mi < 4; ++mi) {
                int r = wr * 64 + mi * 16 + lane15;
                af[mi] = *(const bf16x8*)(As + r * 64 + ((kc * 4 + quad) ^ (r & 7)) * 8);
            }
            #pragma unroll
            for (int ni = 0; ni < 4; ++ni) {
                int r = wc * 64 + ni * 16 + lane15;
                bfr[ni] = *(const bf16x8*)(Bs + r * 64 + ((kc * 4 + quad) ^ (r & 7)) * 8);
            }
            #pragma unroll
            for (int mi = 0; mi < 4; ++mi)
                #pragma unroll
                for (int ni = 0; ni < 4; ++ni)
                    acc[mi][ni] = __builtin_amdgcn_mfma_f32_16x16x32_bf16(
                        af[mi], bfr[ni], acc[mi][ni], 0, 0, 0);
        }
    }

    #pragma unroll
    for (int mi = 0; mi < 4; ++mi)
        #pragma unroll
        for (int ni = 0; ni < 4; ++ni) {
            int col = col0 + wc * 64 + ni * 16 + lane15;
            float bv = bias[col];
            #pragma unroll
            for (int r = 0; r < 4; ++r) {
                int row = row0 + wr * 64 + mi * 16 + quad * 4 + r;
                Cout[(size_t)row * N + col] = acc[mi][ni][r] + bv;
            }
        }
}

// ---------------------------------------------------------------------------
// Flash attention (S^T form), v2: NO K/V LDS staging, NO main-loop barriers.
// K/V fragments are read directly from global (16 KB tiles fit L1; the 4
// waves read identical addresses -> L1 dedups; kfrag/vfrag fit L3).
// Waves run fully independently: each skips its fully-masked causal tiles
// at zero cost, and softmax VALU of one wave overlaps MFMA of another.
// P scratch split per-nq -> ONE lgkmcnt(0) drain per tile (was four).
// LDS: 34.8 KB union (per-wave P scratch | 128x136 epilogue tile).
// ---------------------------------------------------------------------------
__global__ __launch_bounds__(256)
void attn3(const short* __restrict__ qfrag, const short* __restrict__ kfrag,
           const short* __restrict__ vfrag, short* __restrict__ attnb)
{
    __shared__ short SMEM[17408];         // union: P (4w x 2 x 1152) | epi 128x136
    const int tid = threadIdx.x;
    const int lane = tid & 63, w = tid >> 6;
    const int lane15 = lane & 15, quad = lane >> 4;
    const int g = (blockIdx.x + blockIdx.y) & 15;
    const int qb = blockIdx.z ? (15 - g) : g;
    const int h = blockIdx.y, b = blockIdx.z;
    const int bh = b * NHEAD + h;
    const int q0 = qb * 128;
    short* Pw = SMEM + w * 2304;          // per-wave, per-nq regions of 1152

    bf16x8 qf[2][4];
    {
        const short* qp = qfrag + (size_t)bh * 262144
                        + (size_t)(qb * 8 + w * 2) * 2048 + lane * 8;
        #pragma unroll
        for (int nq = 0; nq < 2; ++nq)
            #pragma unroll
            for (int kc = 0; kc < 4; ++kc)
                qf[nq][kc] = *(const bf16x8*)(qp + nq * 2048 + kc * 512);
    }

    f32x4 acc[8][2];
    #pragma unroll
    for (int dt = 0; dt < 8; ++dt)
        #pragma unroll
        for (int nq = 0; nq < 2; ++nq)
            acc[dt][nq] = (f32x4){0.f, 0.f, 0.f, 0.f};
    float m_s[2] = {-3e38f, -3e38f}, l_s[2] = {0.f, 0.f};

    const short* kf_src = kfrag + (size_t)bh * 262144;
    const short* vf_src = vfrag + (size_t)bh * 262144;
    const int qtop = q0 + w * 32 + 31;           // wave's largest q index
    const int kb_end = qtop >> 6;                // last tile with any valid k
    const int diag0 = (q0 + w * 32) >> 6;

    for (int kb = 0; kb <= kb_end; ++kb) {
        const short* Ks = kf_src + (size_t)kb * 8192;
        const short* Vs = vf_src + (size_t)kb * 8192;

        // S^T = K Q^T  (K fragments direct from global/L1)
        f32x4 st[2][4];
        #pragma unroll
        for (int nq = 0; nq < 2; ++nq)
            #pragma unroll
            for (int mi = 0; mi < 4; ++mi)
                st[nq][mi] = (f32x4){0.f, 0.f, 0.f, 0.f};
        #pragma unroll
        for (int mi = 0; mi < 4; ++mi) {
            bf16x8 kf4[4];
            #pragma unroll
            for (int kc = 0; kc < 4; ++kc)
                kf4[kc] = *(const bf16x8*)(Ks + ((mi * 4 + kc) * 64 + lane) * 8);
            #pragma unroll
            for (int kc = 0; kc < 4; ++kc)
                #pragma unroll
                for (int nq = 0; nq < 2; ++nq)
                    st[nq][mi] = __builtin_amdgcn_mfma_f32_16x16x32_bf16(
                        kf4[kc], qf[nq][kc], st[nq][mi], 0, 0, 0);
        }

        if (kb >= diag0) {
            #pragma unroll
            for (int nq = 0; nq < 2; ++nq) {
                int qg = q0 + w * 32 + nq * 16 + lane15;
                #pragma unroll
                for (int mi = 0; mi < 4; ++mi)
                    #pragma unroll
                    for (int r = 0; r < 4; ++r)
                        if (kb * 64 + mi * 16 + quad * 4 + r > qg)
                            st[nq][mi][r] = -3e38f;
            }
        }

        // softmax (online) + P->LDS, both nq written before ONE drain
        #pragma unroll
        for (int nq = 0; nq < 2; ++nq) {
            float mt = st[nq][0][0];
            #pragma unroll
            for (int mi = 0; mi < 4; ++mi)
                #pragma unroll
                for (int r = 0; r < 4; ++r)
                    mt = fmaxf(mt, st[nq][mi][r]);
            mt = fmaxf(mt, __shfl_xor(mt, 16));
            mt = fmaxf(mt, __shfl_xor(mt, 32));
            float mn = fmaxf(m_s[nq], mt);
            float alpha = __expf(m_s[nq] - mn);
            m_s[nq] = mn;
            float sum = 0.f;
            #pragma unroll
            for (int mi = 0; mi < 4; ++mi)
                #pragma unroll
                for (int r = 0; r < 4; ++r) {
                    float p = __expf(st[nq][mi][r] - mn);
                    st[nq][mi][r] = p;
                    sum += p;
                }
            sum += __shfl_xor(sum, 16);
            sum += __shfl_xor(sum, 32);
            l_s[nq] = l_s[nq] * alpha + sum;
            #pragma unroll
            for (int dt = 0; dt < 8; ++dt) {
                acc[dt][nq][0] *= alpha; acc[dt][nq][1] *= alpha;
                acc[dt][nq][2] *= alpha; acc[dt][nq][3] *= alpha;
            }
            short* pr = Pw + nq * 1152 + lane15 * 72 + quad * 4;
            #pragma unroll
            for (int mi = 0; mi < 4; ++mi) {
                unsigned lo = (unsigned)(unsigned short)f2bf(st[nq][mi][0])
                            | ((unsigned)(unsigned short)f2bf(st[nq][mi][1]) << 16);
                unsigned hi = (unsigned)(unsigned short)f2bf(st[nq][mi][2])
                            | ((unsigned)(unsigned short)f2bf(st[nq][mi][3]) << 16);
                *(unsigned*)(pr + mi * 16)     = lo;
                *(unsigned*)(pr + mi * 16 + 2) = hi;
            }
        }
        __asm__ volatile("s_waitcnt lgkmcnt(0)" ::: "memory");
        __builtin_amdgcn_sched_barrier(0);
        bf16x8 pb[2][2];
        #pragma unroll
        for (int nq = 0; nq < 2; ++nq)
            #pragma unroll
            for (int kc2 = 0; kc2 < 2; ++kc2)
                pb[nq][kc2] = *(const bf16x8*)(Pw + nq * 1152 + lane15 * 72
                                               + kc2 * 32 + quad * 8);

        // O^T += V^T P^T  (V fragments direct from global/L1)
        #pragma unroll
        for (int dt = 0; dt < 8; ++dt)
            #pragma unroll
            for (int kc2 = 0; kc2 < 2; ++kc2) {
                bf16x8 vf = *(const bf16x8*)(Vs + ((dt * 2 + kc2) * 64 + lane) * 8);
                #pragma unroll
                for (int nq = 0; nq < 2; ++nq)
                    acc[dt][nq] = __builtin_amdgcn_mfma_f32_16x16x32_bf16(
                        vf, pb[nq][kc2], acc[dt][nq], 0, 0, 0);
            }
    }

    // epilogue: O^T/l -> LDS transpose -> coalesced bf16 store
    __syncthreads();                      // all waves done with P scratch
    short* Eb = SMEM;                     // 128 x 136
    #pragma unroll
    for (int nq = 0; nq < 2; ++nq) {
        float inv = 1.f / l_s[nq];
        int qrow = w * 32 + nq * 16 + lane15;
        #pragma unroll
        for (int dt = 0; dt < 8; ++dt) {
            unsigned lo = (unsigned)(unsigned short)f2bf(acc[dt][nq][0] * inv)
                        | ((unsigned)(unsigned short)f2bf(acc[dt][nq][1] * inv) << 16);
            unsigned hi = (unsigned)(unsigned short)f2bf(acc[dt][nq][2] * inv)
                        | ((unsigned)(unsigned short)f2bf(acc[dt][nq][3] * inv) << 16);
            *(unsigned*)(Eb + qrow * 136 + dt * 16 + quad * 4)     = lo;
            *(unsigned*)(Eb + qrow * 136 + dt * 16 + quad * 4 + 2) = hi;
        }
    }
    __syncthreads();
    {
        int r = tid >> 1, half = tid & 1;
        short* orow = attnb + (size_t)(b * TSEQ + q0 + r) * DM + h * 128 + half * 64;
        #pragma unroll
        for (int i = 0; i < 8; ++i)
            *(bf16x8*)(orow + i * 8) =
                *(const bf16x8*)(Eb + r * 136 + half * 64 + i * 8);
    }
}

// ---------------------------------------------------------------------------
extern "C" void kernel_launch(void* const* d_in, const int* in_sizes, int n_in,
                              void* d_out, int out_size, void* d_ws, size_t ws_size,
                              hipStream_t stream)
{
    const float* x     = (const float*)d_in[0];
    const float* w_qkv = (const float*)d_in[1];
    const float* b_qkv = (const float*)d_in[2];
    const float* w_out = (const float*)d_in[3];
    const float* b_out = (const float*)d_in[4];
    float* out = (float*)d_out;

    char* ws = (char*)d_ws;
    short* xb    = (short*)(ws);                 // 16.78 MB (reused as attnb)
    short* wqkvb = (short*)(ws + 16777216);      // 25.17 MB
    short* woutb = (short*)(ws + 41943040);      //  8.39 MB
    short* qfrag = (short*)(ws + 50331648);      // 16.78 MB
    short* kfrag = (short*)(ws + 67108864);      // 16.78 MB
    short* vfrag = (short*)(ws + 83886080);      // 16.78 MB  (total 100.66 MB)
    short* attnb = xb;                           // x dead after QKV GEMM

    cast_all<<<12288, 256, 0, stream>>>(x, xb, w_qkv, wqkvb, w_out, woutb);

    {   // qkv GEMM + bias + rope + fragment repack (256^2 8-phase)
        dim3 g2(24, 16);
        gemm_qkv_rope<<<g2, 512, 0, stream>>>(xb, wqkvb, b_qkv, qfrag, kfrag, vfrag);
    }
    {   // flash attention
        dim3 g2(16, NHEAD, BATCH);
        attn3<<<g2, 256, 0, stream>>>(qfrag, kfrag, vfrag, attnb);
    }
    {   // out = attn @ w_out^T + b_out
        dim3 g2(16, 32);
        gemm_out<<<g2, 256, 0, stream>>>(attnb, woutb, b_out, out, 2048, 2048);
    }
}

// Round 4
// 381.267 us; speedup vs baseline: 1.2715x; 1.2715x over previous
//
#include <hip/hip_runtime.h>
#include <math.h>

#define NHEAD 16
#define TSEQ  2048
#define BATCH 2
#define DM    2048

typedef __attribute__((ext_vector_type(8))) short bf16x8;
typedef __attribute__((ext_vector_type(4))) float f32x4;

__device__ __forceinline__ short f2bf(float f) {
    unsigned u = __builtin_bit_cast(unsigned, f);
    u += 0x7fff + ((u >> 16) & 1);          // RNE
    return (short)(u >> 16);
}
__device__ __forceinline__ float bf2f(short s) {
    unsigned u = ((unsigned)(unsigned short)s) << 16;
    return __builtin_bit_cast(float, u);
}
__device__ __forceinline__ void gload_lds16(const void* g, void* l) {
    __builtin_amdgcn_global_load_lds(
        (const __attribute__((address_space(1))) unsigned int*)g,
        (__attribute__((address_space(3))) unsigned int*)l, 16, 0, 0);
}

// ---------------------------------------------------------------------------
// merged fp32->bf16 casts: x (8.39M), w_qkv (12.58M), w_out (4.19M)
// ---------------------------------------------------------------------------
__global__ __launch_bounds__(256)
void cast_all(const float* __restrict__ x, short* __restrict__ xb,
              const float* __restrict__ wq, short* __restrict__ wqb,
              const float* __restrict__ wo, short* __restrict__ wob)
{
    int bid = blockIdx.x;
    const float* src; short* dst; int lb;
    if (bid < 4096)       { src = x;  dst = xb;  lb = bid; }
    else if (bid < 10240) { src = wq; dst = wqb; lb = bid - 4096; }
    else                  { src = wo; dst = wob; lb = bid - 10240; }
    int i = (lb * 256 + threadIdx.x) * 8;
    float4 a = *(const float4*)(src + i);
    float4 b = *(const float4*)(src + i + 4);
    bf16x8 o;
    o[0]=f2bf(a.x); o[1]=f2bf(a.y); o[2]=f2bf(a.z); o[3]=f2bf(a.w);
    o[4]=f2bf(b.x); o[5]=f2bf(b.y); o[6]=f2bf(b.z); o[7]=f2bf(b.w);
    *(bf16x8*)(dst + i) = o;
}

// ---------------------------------------------------------------------------
// QKV GEMM v3: 128x256 tile, BK=64, 8 waves (2Mx4N, wave=64x64), 3-buffer
// LDS ring staged 2 K-tiles ahead (counted vmcnt(6), never 0 mid-loop),
// 2 phases per K-tile (16 MFMA + 8 balanced ds_reads each), setprio around
// MFMA, chunk-XOR swizzle via pre-swizzled global source (T2-compatible).
// Grid 24x32 = 768 blocks = exactly 3 full rounds at 1 block/CU -> no tail.
// Fused bias + RoPE + fragment repack epilogue (two 128-col q/k/v chunks).
// qfrag/kfrag: [bh][t16][kc4][lane64][8]   (attn B-operand layout)
// vfrag:       [bh][kb64][dt8][kc2][lane64][8] (V^T A-operand layout)
// ---------------------------------------------------------------------------
#define BARRIER() __builtin_amdgcn_s_barrier()
#define WAIT_LGKM0() do { asm volatile("s_waitcnt lgkmcnt(0)" ::: "memory"); \
                          __builtin_amdgcn_sched_barrier(0); } while (0)
#define WAIT_VM(N) asm volatile("s_waitcnt vmcnt(" #N ")" ::: "memory")

// stage K-tile T into ring buffer T%3: A 128x64 (2 loads/thread) then
// B 256x64 (4 loads/thread). Linear LDS dest + pre-swizzled global source.
#define STAGE(T) do { if ((T) < 32) {                                         \
    short* dst_ = sm + ((T) % 3) * 24576;                                     \
    const int kt_ = (T) << 6;                                                 \
    _Pragma("unroll")                                                         \
    for (int i_ = 0; i_ < 2; ++i_) {                                          \
        int ci_ = i_*512 + tid;                                               \
        int r_ = ci_ >> 3, lc_ = ci_ & 7;                                     \
        gload_lds16(A + (size_t)(row0 + r_)*2048 + kt_ + ((lc_ ^ (r_ & 7)) << 3), \
                    dst_ + ci_*8);                                            \
    }                                                                         \
    _Pragma("unroll")                                                         \
    for (int i_ = 0; i_ < 4; ++i_) {                                          \
        int ci_ = i_*512 + tid;                                               \
        int r_ = ci_ >> 3, lc_ = ci_ & 7;                                     \
        gload_lds16(W + (size_t)(col0 + r_)*2048 + kt_ + ((lc_ ^ (r_ & 7)) << 3), \
                    dst_ + 8192 + ci_*8);                                     \
    } } } while (0)

#define LOADRD(Ab, Bb, KC) do {                                               \
    _Pragma("unroll")                                                         \
    for (int m_ = 0; m_ < 4; ++m_) {                                          \
        int r_ = wr*64 + m_*16 + lane15;                                      \
        af[m_] = *(const bf16x8*)((Ab) + r_*64 + ((((KC)*4 + quad) ^ (r_ & 7)) << 3)); \
    }                                                                         \
    _Pragma("unroll")                                                         \
    for (int n_ = 0; n_ < 4; ++n_) {                                          \
        int r_ = wc*64 + n_*16 + lane15;                                      \
        bb[n_] = *(const bf16x8*)((Bb) + r_*64 + ((((KC)*4 + quad) ^ (r_ & 7)) << 3)); \
    }                                                                         \
} while (0)

#define MMA16() do {                                                          \
    _Pragma("unroll")                                                         \
    for (int m_ = 0; m_ < 4; ++m_)                                            \
        _Pragma("unroll")                                                     \
        for (int n_ = 0; n_ < 4; ++n_)                                        \
            acc[m_][n_] = __builtin_amdgcn_mfma_f32_16x16x32_bf16(            \
                af[m_], bb[n_], acc[m_][n_], 0, 0, 0);                        \
} while (0)

__global__ __launch_bounds__(512, 2)
void gemm_qkv_rope(const short* __restrict__ A, const short* __restrict__ W,
                   const float* __restrict__ bias, short* __restrict__ qfrag,
                   short* __restrict__ kfrag, short* __restrict__ vfrag)
{
    __shared__ short sm[73728];          // 144 KiB: 3 bufs x (A 8192 | B 16384)
    const int tid = threadIdx.x;
    const int lane = tid & 63, w = tid >> 6;
    const int lane15 = lane & 15, quad = lane >> 4;
    const int wr = w >> 2, wc = w & 3;   // 2M x 4N waves, wave tile 64x64
    const int row0 = blockIdx.y * 128, col0 = blockIdx.x * 256;

    f32x4 acc[4][4];
    #pragma unroll
    for (int mi = 0; mi < 4; ++mi)
        #pragma unroll
        for (int ni = 0; ni < 4; ++ni)
            acc[mi][ni] = (f32x4){0.f, 0.f, 0.f, 0.f};

    bf16x8 af[4], bb[4];

    // prologue: stage tiles 0,1 (12 loads/thread); t0 complete, t1 in flight
    STAGE(0); STAGE(1);
    WAIT_VM(6);
    BARRIER();

    for (int t = 0; t < 32; ++t) {
        short* Ab = sm + (t % 3) * 24576;
        short* Bb = Ab + 8192;
        // ---- p1 (kc=0): read cur, stage t+2 into buf[(t-1)%3] (dead)
        LOADRD(Ab, Bb, 0);
        STAGE(t + 2);
        BARRIER(); WAIT_LGKM0();
        __builtin_amdgcn_s_setprio(1); MMA16(); __builtin_amdgcn_s_setprio(0);
        BARRIER();
        // ---- p2 (kc=1): counted wait -> tile t+1 complete before next p1
        LOADRD(Ab, Bb, 1);
        if (t < 30) { WAIT_VM(6); } else { WAIT_VM(0); }
        BARRIER(); WAIT_LGKM0();
        __builtin_amdgcn_s_setprio(1); MMA16(); __builtin_amdgcn_s_setprio(0);
        BARRIER();
    }

    // ---- epilogue: two 128-col chunks, each one q/k/v type of one head ----
    const int b = row0 >> 11;
    const int t0g = row0 & 2047;
    #pragma unroll
    for (int ch = 0; ch < 2; ++ch) {
        const int cidx = (blockIdx.x << 1) + ch;      // global 128-col index
        const int head = cidx / 3, type = cidx % 3;   // 0=q 1=k 2=v
        __syncthreads();
        if ((wc >> 1) == ch) {                        // waves owning these cols
            #pragma unroll
            for (int ni = 0; ni < 4; ++ni) {
                int d = (wc & 1)*64 + ni*16 + lane15;
                float bv = bias[col0 + ch*128 + d];
                #pragma unroll
                for (int mi = 0; mi < 4; ++mi) {
                    int rowb = wr*64 + mi*16 + quad*4;
                    #pragma unroll
                    for (int r = 0; r < 4; ++r)
                        sm[(rowb + r)*136 + d] = f2bf(acc[mi][ni][r] + bv);
                }
            }
        }
        __syncthreads();
        if (type < 2) {   // q or k: rope + frag store (128 rows x 128 cols)
            const float sc = (type == 0) ? 0.022097086912079608f : 1.0f;
            short* dst = (type == 0 ? qfrag : kfrag) + (size_t)(b*NHEAD + head)*262144;
            #pragma unroll
            for (int it = 0; it < 2; ++it) {
                int c = it*512 + tid;                 // [0,1024)
                int l15 = c & 15, q_ = (c >> 4) & 3, kc = (c >> 6) & 1, rowhi = c >> 7;
                int lrow = rowhi*16 + l15;            // [0,128)
                int t = t0g + lrow;
                bf16x8 a8 = *(const bf16x8*)(sm + lrow*136 + kc*32 + q_*8);
                bf16x8 b8 = *(const bf16x8*)(sm + lrow*136 + kc*32 + q_*8 + 64);
                bf16x8 oa, ob;
                #pragma unroll
                for (int j = 0; j < 8; ++j) {
                    int d = kc*32 + q_*8 + j;
                    // theta_rev = 10000^(-d/64) / (2*pi)
                    float trev = exp2f(-(float)d * (13.287712379549449f / 64.0f))
                                 * 0.15915494309189535f;
                    float ang = (float)t * trev;
                    float fr = ang - floorf(ang);
                    float sn, cs;
                    __sincosf(fr * 6.283185307179586f, &sn, &cs);
                    float va = bf2f(a8[j]), vb = bf2f(b8[j]);
                    oa[j] = f2bf((va*cs - vb*sn)*sc);
                    ob[j] = f2bf((va*sn + vb*cs)*sc);
                }
                size_t base = (size_t)((t0g >> 4) + rowhi)*2048 + (q_*16 + l15)*8;
                *(bf16x8*)(dst + base + kc*512)        = oa;
                *(bf16x8*)(dst + base + kc*512 + 1024) = ob;
            }
        } else {          // v: transpose to vfrag (128 rows -> 2 kb groups)
            short* dst = vfrag + (size_t)(b*NHEAD + head)*262144;
            #pragma unroll
            for (int it = 0; it < 4; ++it) {
                int c = it*512 + tid;                 // [0,2048)
                int lane_ = c & 63, rest = c >> 6;    // [0,32)
                int q_ = lane_ >> 4, l15 = lane_ & 15;
                int dt = rest & 7, kc2 = (rest >> 3) & 1, kbt = rest >> 4;  // {0,1}
                int d = dt*16 + l15;
                bf16x8 v;
                #pragma unroll
                for (int j = 0; j < 8; ++j)
                    v[j] = sm[(kbt*64 + kc2*32 + q_*8 + j)*136 + d];
                *(bf16x8*)(dst + (size_t)((t0g >> 6) + kbt)*8192
                            + dt*1024 + kc2*512 + lane_*8) = v;
            }
        }
    }
}

// ---------------------------------------------------------------------------
// bf16 MFMA GEMM (NT) for out-projection (unchanged, fp32 out).
// ---------------------------------------------------------------------------
__global__ __launch_bounds__(256)
void gemm_out(const short* __restrict__ A, const short* __restrict__ W,
              const float* __restrict__ bias, float* __restrict__ Cout,
              int N, int K)
{
    __shared__ short As[128 * 64];
    __shared__ short Bs[128 * 64];
    const int tid = threadIdx.x;
    const int lane = tid & 63, w = tid >> 6;
    const int lane15 = lane & 15, quad = lane >> 4;
    const int wr = w >> 1, wc = w & 1;
    const int row0 = blockIdx.y * 128, col0 = blockIdx.x * 128;

    f32x4 acc[4][4];
    #pragma unroll
    for (int mi = 0; mi < 4; ++mi)
        #pragma unroll
        for (int ni = 0; ni < 4; ++ni)
            acc[mi][ni] = (f32x4){0.f, 0.f, 0.f, 0.f};

    for (int kt = 0; kt < K; kt += 64) {
        __syncthreads();
        #pragma unroll
        for (int i = 0; i < 4; ++i) {
            int ci = i * 256 + tid;
            int row = ci >> 3, lc = ci & 7;
            int gc = lc ^ (row & 7);
            gload_lds16(A + (size_t)(row0 + row) * K + kt + gc * 8, As + ci * 8);
            gload_lds16(W + (size_t)(col0 + row) * K + kt + gc * 8, Bs + ci * 8);
        }
        __syncthreads();
        #pragma unroll
        for (int kc = 0; kc < 2; ++kc) {
            bf16x8 af[4], bfr[4];
            #pragma unroll
            for (int mi = 0; mi < 4; ++mi) {
                int r = wr * 64 + mi * 16 + lane15;
                af[mi] = *(const bf16x8*)(As + r * 64 + ((kc * 4 + quad) ^ (r & 7)) * 8);
            }
            #pragma unroll
            for (int ni = 0; ni < 4; ++ni) {
                int r = wc * 64 + ni * 16 + lane15;
                bfr[ni] = *(const bf16x8*)(Bs + r * 64 + ((kc * 4 + quad) ^ (r & 7)) * 8);
            }
            #pragma unroll
            for (int mi = 0; mi < 4; ++mi)
                #pragma unroll
                for (int ni = 0; ni < 4; ++ni)
                    acc[mi][ni] = __builtin_amdgcn_mfma_f32_16x16x32_bf16(
                        af[mi], bfr[ni], acc[mi][ni], 0, 0, 0);
        }
    }

    #pragma unroll
    for (int mi = 0; mi < 4; ++mi)
        #pragma unroll
        for (int ni = 0; ni < 4; ++ni) {
            int col = col0 + wc * 64 + ni * 16 + lane15;
            float bv = bias[col];
            #pragma unroll
            for (int r = 0; r < 4; ++r) {
                int row = row0 + wr * 64 + mi * 16 + quad * 4 + r;
                Cout[(size_t)row * N + col] = acc[mi][ni][r] + bv;
            }
        }
}

// ---------------------------------------------------------------------------
// Flash attention (S^T form) with double-buffered K/V staging (round-1
// verified version: barrier -> issue DMA(kb+1 -> buf^1) -> compute(buf)).
// ---------------------------------------------------------------------------
__global__ __launch_bounds__(256)
void attn3(const short* __restrict__ qfrag, const short* __restrict__ kfrag,
           const short* __restrict__ vfrag, short* __restrict__ attnb)
{
    __shared__ short KV[2][16384];        // per buf: K 8192 | V 8192 shorts
    __shared__ short Pb[4][1152];         // per wave: 16 q x stride 72
    const int tid = threadIdx.x;
    const int lane = tid & 63, w = tid >> 6;
    const int lane15 = lane & 15, quad = lane >> 4;
    const int g = (blockIdx.x + blockIdx.y) & 15;
    const int qb = blockIdx.z ? (15 - g) : g;
    const int h = blockIdx.y, b = blockIdx.z;
    const int bh = b * NHEAD + h;
    const int q0 = qb * 128;
    short* Pw = Pb[w];

    bf16x8 qf[2][4];
    {
        const short* qp = qfrag + (size_t)bh * 262144
                        + (size_t)(qb * 8 + w * 2) * 2048 + lane * 8;
        #pragma unroll
        for (int nq = 0; nq < 2; ++nq)
            #pragma unroll
            for (int kc = 0; kc < 4; ++kc)
                qf[nq][kc] = *(const bf16x8*)(qp + nq * 2048 + kc * 512);
    }

    f32x4 acc[8][2];
    #pragma unroll
    for (int dt = 0; dt < 8; ++dt)
        #pragma unroll
        for (int nq = 0; nq < 2; ++nq)
            acc[dt][nq] = (f32x4){0.f, 0.f, 0.f, 0.f};
    float m_s[2] = {-3e38f, -3e38f}, l_s[2] = {0.f, 0.f};

    const short* kf_src = kfrag + (size_t)bh * 262144;
    const short* vf_src = vfrag + (size_t)bh * 262144;
    const int kb_max = 2 * qb + 1;
    const int qtop = q0 + w * 32 + 31;           // wave's largest q index
    const int diag0 = (q0 + w * 32) >> 6;

    // prologue DMA for kb=0
    #pragma unroll
    for (int i = 0; i < 4; ++i) {
        int ci = i * 256 + tid;
        gload_lds16(kf_src + ci * 8, KV[0] + ci * 8);
        gload_lds16(vf_src + ci * 8, KV[0] + 8192 + ci * 8);
    }

    for (int kb = 0; kb <= kb_max; ++kb) {
        __syncthreads();                           // drains buf[kb&1] DMA
        if (kb < kb_max) {                         // prefetch next tile
            const short* ks = kf_src + (size_t)(kb + 1) * 8192;
            const short* vs = vf_src + (size_t)(kb + 1) * 8192;
            short* kd = KV[(kb + 1) & 1];
            #pragma unroll
            for (int i = 0; i < 4; ++i) {
                int ci = i * 256 + tid;
                gload_lds16(ks + ci * 8, kd + ci * 8);
                gload_lds16(vs + ci * 8, kd + 8192 + ci * 8);
            }
        }
        if (kb * 64 > qtop) continue;              // fully masked for this wave
        const short* Ks = KV[kb & 1];
        const short* Vs = Ks + 8192;

        // S^T = K Q^T
        f32x4 st[2][4];
        #pragma unroll
        for (int nq = 0; nq < 2; ++nq)
            #pragma unroll
            for (int mi = 0; mi < 4; ++mi)
                st[nq][mi] = (f32x4){0.f, 0.f, 0.f, 0.f};
        #pragma unroll
        for (int mi = 0; mi < 4; ++mi) {
            bf16x8 kf4[4];
            #pragma unroll
            for (int kc = 0; kc < 4; ++kc)
                kf4[kc] = *(const bf16x8*)(Ks + ((mi * 4 + kc) * 64 + lane) * 8);
            #pragma unroll
            for (int kc = 0; kc < 4; ++kc)
                #pragma unroll
                for (int nq = 0; nq < 2; ++nq)
                    st[nq][mi] = __builtin_amdgcn_mfma_f32_16x16x32_bf16(
                        kf4[kc], qf[nq][kc], st[nq][mi], 0, 0, 0);
        }

        if (kb >= diag0) {
            #pragma unroll
            for (int nq = 0; nq < 2; ++nq) {
                int qg = q0 + w * 32 + nq * 16 + lane15;
                #pragma unroll
                for (int mi = 0; mi < 4; ++mi)
                    #pragma unroll
                    for (int r = 0; r < 4; ++r)
                        if (kb * 64 + mi * 16 + quad * 4 + r > qg)
                            st[nq][mi][r] = -3e38f;
            }
        }

        // softmax + P->LDS (halved buffer, reused across the two nq halves)
        bf16x8 pb[2][2];
        #pragma unroll
        for (int nq = 0; nq < 2; ++nq) {
            float mt = st[nq][0][0];
            #pragma unroll
            for (int mi = 0; mi < 4; ++mi)
                #pragma unroll
                for (int r = 0; r < 4; ++r)
                    mt = fmaxf(mt, st[nq][mi][r]);
            mt = fmaxf(mt, __shfl_xor(mt, 16));
            mt = fmaxf(mt, __shfl_xor(mt, 32));
            float mn = fmaxf(m_s[nq], mt);
            float alpha = __expf(m_s[nq] - mn);
            m_s[nq] = mn;
            float sum = 0.f;
            #pragma unroll
            for (int mi = 0; mi < 4; ++mi)
                #pragma unroll
                for (int r = 0; r < 4; ++r) {
                    float p = __expf(st[nq][mi][r] - mn);
                    st[nq][mi][r] = p;
                    sum += p;
                }
            sum += __shfl_xor(sum, 16);
            sum += __shfl_xor(sum, 32);
            l_s[nq] = l_s[nq] * alpha + sum;
            #pragma unroll
            for (int dt = 0; dt < 8; ++dt) {
                acc[dt][nq][0] *= alpha; acc[dt][nq][1] *= alpha;
                acc[dt][nq][2] *= alpha; acc[dt][nq][3] *= alpha;
            }
            short* pr = Pw + lane15 * 72 + quad * 4;
            #pragma unroll
            for (int mi = 0; mi < 4; ++mi) {
                unsigned lo = (unsigned)(unsigned short)f2bf(st[nq][mi][0])
                            | ((unsigned)(unsigned short)f2bf(st[nq][mi][1]) << 16);
                unsigned hi = (unsigned)(unsigned short)f2bf(st[nq][mi][2])
                            | ((unsigned)(unsigned short)f2bf(st[nq][mi][3]) << 16);
                *(unsigned*)(pr + mi * 16)     = lo;
                *(unsigned*)(pr + mi * 16 + 2) = hi;
            }
            __asm__ volatile("s_waitcnt lgkmcnt(0)" ::: "memory");
            #pragma unroll
            for (int kc2 = 0; kc2 < 2; ++kc2)
                pb[nq][kc2] = *(const bf16x8*)(Pw + lane15 * 72 + kc2 * 32 + quad * 8);
            __asm__ volatile("s_waitcnt lgkmcnt(0)" ::: "memory");  // reads done before nq=1 overwrite
        }

        // O^T += V^T P^T  (each V fragment feeds both nq)
        #pragma unroll
        for (int dt = 0; dt < 8; ++dt)
            #pragma unroll
            for (int kc2 = 0; kc2 < 2; ++kc2) {
                bf16x8 vf = *(const bf16x8*)(Vs + ((dt * 2 + kc2) * 64 + lane) * 8);
                #pragma unroll
                for (int nq = 0; nq < 2; ++nq)
                    acc[dt][nq] = __builtin_amdgcn_mfma_f32_16x16x32_bf16(
                        vf, pb[nq][kc2], acc[dt][nq], 0, 0, 0);
            }
    }

    // epilogue: O^T/l -> LDS transpose -> coalesced bf16 store
    __syncthreads();
    short* Eb = KV[0];                    // 128 x 136
    #pragma unroll
    for (int nq = 0; nq < 2; ++nq) {
        float inv = 1.f / l_s[nq];
        int qrow = w * 32 + nq * 16 + lane15;
        #pragma unroll
        for (int dt = 0; dt < 8; ++dt) {
            unsigned lo = (unsigned)(unsigned short)f2bf(acc[dt][nq][0] * inv)
                        | ((unsigned)(unsigned short)f2bf(acc[dt][nq][1] * inv) << 16);
            unsigned hi = (unsigned)(unsigned short)f2bf(acc[dt][nq][2] * inv)
                        | ((unsigned)(unsigned short)f2bf(acc[dt][nq][3] * inv) << 16);
            *(unsigned*)(Eb + qrow * 136 + dt * 16 + quad * 4)     = lo;
            *(unsigned*)(Eb + qrow * 136 + dt * 16 + quad * 4 + 2) = hi;
        }
    }
    __syncthreads();
    {
        int r = tid >> 1, half = tid & 1;
        short* orow = attnb + (size_t)(b * TSEQ + q0 + r) * DM + h * 128 + half * 64;
        #pragma unroll
        for (int i = 0; i < 8; ++i)
            *(bf16x8*)(orow + i * 8) =
                *(const bf16x8*)(Eb + r * 136 + half * 64 + i * 8);
    }
}

// ---------------------------------------------------------------------------
extern "C" void kernel_launch(void* const* d_in, const int* in_sizes, int n_in,
                              void* d_out, int out_size, void* d_ws, size_t ws_size,
                              hipStream_t stream)
{
    const float* x     = (const float*)d_in[0];
    const float* w_qkv = (const float*)d_in[1];
    const float* b_qkv = (const float*)d_in[2];
    const float* w_out = (const float*)d_in[3];
    const float* b_out = (const float*)d_in[4];
    float* out = (float*)d_out;

    char* ws = (char*)d_ws;
    short* xb    = (short*)(ws);                 // 16.78 MB (reused as attnb)
    short* wqkvb = (short*)(ws + 16777216);      // 25.17 MB
    short* woutb = (short*)(ws + 41943040);      //  8.39 MB
    short* qfrag = (short*)(ws + 50331648);      // 16.78 MB
    short* kfrag = (short*)(ws + 67108864);      // 16.78 MB
    short* vfrag = (short*)(ws + 83886080);      // 16.78 MB  (total 100.66 MB)
    short* attnb = xb;                           // x dead after QKV GEMM

    cast_all<<<12288, 256, 0, stream>>>(x, xb, w_qkv, wqkvb, w_out, woutb);

    {   // qkv GEMM + bias + rope + fragment repack (128x256, ring-3, no tail)
        dim3 g2(24, 32);
        gemm_qkv_rope<<<g2, 512, 0, stream>>>(xb, wqkvb, b_qkv, qfrag, kfrag, vfrag);
    }
    {   // flash attention
        dim3 g2(16, NHEAD, BATCH);
        attn3<<<g2, 256, 0, stream>>>(qfrag, kfrag, vfrag, attnb);
    }
    {   // out = attn @ w_out^T + b_out
        dim3 g2(16, 32);
        gemm_out<<<g2, 256, 0, stream>>>(attnb, woutb, b_out, out, 2048, 2048);
    }
}

// Round 5
// 380.775 us; speedup vs baseline: 1.2731x; 1.0013x over previous
//
#include <hip/hip_runtime.h>
#include <math.h>

#define NHEAD 16
#define TSEQ  2048
#define BATCH 2
#define DM    2048

typedef __attribute__((ext_vector_type(8))) short bf16x8;
typedef __attribute__((ext_vector_type(4))) float f32x4;

__device__ __forceinline__ short f2bf(float f) {
    unsigned u = __builtin_bit_cast(unsigned, f);
    u += 0x7fff + ((u >> 16) & 1);          // RNE
    return (short)(u >> 16);
}
__device__ __forceinline__ float bf2f(short s) {
    unsigned u = ((unsigned)(unsigned short)s) << 16;
    return __builtin_bit_cast(float, u);
}
__device__ __forceinline__ void gload_lds16(const void* g, void* l) {
    __builtin_amdgcn_global_load_lds(
        (const __attribute__((address_space(1))) unsigned int*)g,
        (__attribute__((address_space(3))) unsigned int*)l, 16, 0, 0);
}

// ---------------------------------------------------------------------------
// merged fp32->bf16 casts + RoPE cos/sin table ([d][t], 2048x64 float2).
// Table entries computed with the EXACT float sequence the epilogue used
// inline -> bit-identical results.
// ---------------------------------------------------------------------------
__global__ __launch_bounds__(256)
void cast_all(const float* __restrict__ x, short* __restrict__ xb,
              const float* __restrict__ wq, short* __restrict__ wqb,
              const float* __restrict__ wo, short* __restrict__ wob,
              float2* __restrict__ trig)
{
    int bid = blockIdx.x;
    if (bid >= 12288) {                   // trig table (only launched if fits)
        if (trig) {
            int idx = (bid - 12288) * 256 + threadIdx.x;   // d*2048 + t
            int d = idx >> 11, t = idx & 2047;
            float trev = exp2f(-(float)d * (13.287712379549449f / 64.0f))
                         * 0.15915494309189535f;
            float ang = (float)t * trev;
            float fr = ang - floorf(ang);
            float sn, cs;
            __sincosf(fr * 6.283185307179586f, &sn, &cs);
            trig[idx] = make_float2(cs, sn);
        }
        return;
    }
    const float* src; short* dst; int lb;
    if (bid < 4096)       { src = x;  dst = xb;  lb = bid; }
    else if (bid < 10240) { src = wq; dst = wqb; lb = bid - 4096; }
    else                  { src = wo; dst = wob; lb = bid - 10240; }
    int i = (lb * 256 + threadIdx.x) * 8;
    float4 a = *(const float4*)(src + i);
    float4 b = *(const float4*)(src + i + 4);
    bf16x8 o;
    o[0]=f2bf(a.x); o[1]=f2bf(a.y); o[2]=f2bf(a.z); o[3]=f2bf(a.w);
    o[4]=f2bf(b.x); o[5]=f2bf(b.y); o[6]=f2bf(b.z); o[7]=f2bf(b.w);
    *(bf16x8*)(dst + i) = o;
}

// ---------------------------------------------------------------------------
// QKV GEMM: 256x256 tile, BK=64, 8 waves (2Mx4N), 8-phase schedule, counted
// vmcnt, setprio, chunk-XOR swizzle. v4: staging source addresses hoisted to
// per-thread pointers (STAGE = ptr + T*64, one add), RoPE via trig table.
// qfrag/kfrag: [bh][t16][kc4][lane64][8]   (attn operand layout)
// vfrag:       [bh][kb64][dt8][kc2][lane64][8] (V^T A-operand layout)
// ---------------------------------------------------------------------------
#define BARRIER() __builtin_amdgcn_s_barrier()
#define WAIT_LGKM0() do { asm volatile("s_waitcnt lgkmcnt(0)" ::: "memory"); \
                          __builtin_amdgcn_sched_barrier(0); } while (0)
#define WAIT_VM(N) asm volatile("s_waitcnt vmcnt(" #N ")" ::: "memory")

#define LOAD_A(BUF, MH) do {                                                  \
    const short* base_ = sm + (BUF)*32768 + (MH)*8192;                        \
    _Pragma("unroll")                                                         \
    for (int m_ = 0; m_ < 4; ++m_) {                                          \
        int j_ = wr*64 + m_*16 + lane15;                                      \
        const short* rp_ = base_ + j_*64;                                     \
        int sw_ = (j_ & 7) << 3;                                              \
        af[m_][0] = *(const bf16x8*)(rp_ + ((quad << 3) ^ sw_));              \
        af[m_][1] = *(const bf16x8*)(rp_ + ((32 + (quad << 3)) ^ sw_));       \
    }                                                                         \
} while (0)

#define LOAD_B(BUF, NH, BB) do {                                              \
    const short* base_ = sm + (BUF)*32768 + 16384 + (NH)*8192;                \
    _Pragma("unroll")                                                         \
    for (int n_ = 0; n_ < 2; ++n_) {                                          \
        int j_ = wc*32 + n_*16 + lane15;                                      \
        const short* rp_ = base_ + j_*64;                                     \
        int sw_ = (j_ & 7) << 3;                                              \
        BB[n_][0] = *(const bf16x8*)(rp_ + ((quad << 3) ^ sw_));              \
        BB[n_][1] = *(const bf16x8*)(rp_ + ((32 + (quad << 3)) ^ sw_));       \
    }                                                                         \
} while (0)

// hoisted-pointer staging: src = pXsrc[i_][half] + T*64 (shorts)
#define STAGE_A(T, MH, BUFOFF) do { if ((T) < 32) {                           \
    short* dst_ = sm + (BUFOFF) + ((MH) << 13);                               \
    _Pragma("unroll")                                                         \
    for (int i_ = 0; i_ < 2; ++i_)                                            \
        gload_lds16(pAsrc[i_][MH] + ((T) << 6), dst_ + (i_*512 + tid)*8);     \
    } } while (0)

#define STAGE_B(T, NH, BUFOFF) do { if ((T) < 32) {                           \
    short* dst_ = sm + (BUFOFF) + 16384 + ((NH) << 13);                       \
    _Pragma("unroll")                                                         \
    for (int i_ = 0; i_ < 2; ++i_)                                            \
        gload_lds16(pWsrc[i_][NH] + ((T) << 6), dst_ + (i_*512 + tid)*8);     \
    } } while (0)

#define MMA_Q(MH, NH, BB) do {                                                \
    _Pragma("unroll")                                                         \
    for (int m_ = 0; m_ < 4; ++m_) {                                          \
        _Pragma("unroll")                                                     \
        for (int n_ = 0; n_ < 2; ++n_) {                                      \
            f32x4 c_ = acc[(MH)*4 + m_][(NH)*2 + n_];                         \
            c_ = __builtin_amdgcn_mfma_f32_16x16x32_bf16(af[m_][0], BB[n_][0], c_, 0, 0, 0); \
            c_ = __builtin_amdgcn_mfma_f32_16x16x32_bf16(af[m_][1], BB[n_][1], c_, 0, 0, 0); \
            acc[(MH)*4 + m_][(NH)*2 + n_] = c_;                               \
        }                                                                     \
    }                                                                         \
} while (0)

__global__ __launch_bounds__(512, 2)
void gemm_qkv_rope(const short* __restrict__ A, const short* __restrict__ W,
                   const float* __restrict__ bias, short* __restrict__ qfrag,
                   short* __restrict__ kfrag, short* __restrict__ vfrag,
                   const float2* __restrict__ trig)
{
    __shared__ short sm[65536];                  // 128 KiB: 2 buf x (A 32K | B 32K)
    const int tid = threadIdx.x;
    const int lane = tid & 63, w = tid >> 6;
    const int lane15 = lane & 15, quad = lane >> 4;
    const int wr = w >> 2, wc = w & 3;           // 2M x 4N waves
    const int row0 = blockIdx.y * 256, col0 = blockIdx.x * 256;

    // per-thread invariant staging sources (swizzle folded in)
    const short* pAsrc[2][2];
    const short* pWsrc[2][2];
    #pragma unroll
    for (int i_ = 0; i_ < 2; ++i_) {
        int ci = i_*512 + tid, j = ci >> 3, lc = ci & 7;
        int swz = (lc ^ (j & 7)) << 3;
        #pragma unroll
        for (int h = 0; h < 2; ++h) {
            pAsrc[i_][h] = A + (size_t)(row0 + (j & 63) + ((j >> 6) << 7) + h*64) * 2048 + swz;
            pWsrc[i_][h] = W + (size_t)(col0 + (j & 31) + ((j >> 5) << 6) + h*32) * 2048 + swz;
        }
    }

    f32x4 acc[8][4];
    #pragma unroll
    for (int mi = 0; mi < 8; ++mi)
        #pragma unroll
        for (int ni = 0; ni < 4; ++ni)
            acc[mi][ni] = (f32x4){0.f, 0.f, 0.f, 0.f};

    bf16x8 af[4][2], bb0[2][2], bb1[2][2];

    // prologue: stage tiles 0 (buf0) and 1 (buf1); keep tile1 in flight
    STAGE_A(0, 0, 0);     STAGE_B(0, 0, 0);
    STAGE_A(0, 1, 0);     STAGE_B(0, 1, 0);
    STAGE_A(1, 0, 32768); STAGE_B(1, 0, 32768);
    STAGE_A(1, 1, 32768); STAGE_B(1, 1, 32768);
    WAIT_VM(8);
    BARRIER();

    for (int i = 0; i < 16; ++i) {
        const int ta = 2*i + 2;                  // -> buf0
        const int tb = 2*i + 3;                  // -> buf1
        // ---- p1: Q(0,0) on buf0
        LOAD_A(0, 0);
        LOAD_B(0, 0, bb0);
        BARRIER(); WAIT_LGKM0();
        __builtin_amdgcn_s_setprio(1); MMA_Q(0, 0, bb0); __builtin_amdgcn_s_setprio(0);
        BARRIER();
        // ---- p2: Q(0,1)   (A'0/B'0 slots of buf0 now dead -> stage ta)
        LOAD_B(0, 1, bb1);
        STAGE_A(ta, 0, 0); STAGE_B(ta, 0, 0);
        BARRIER(); WAIT_LGKM0();
        __builtin_amdgcn_s_setprio(1); MMA_Q(0, 1, bb1); __builtin_amdgcn_s_setprio(0);
        BARRIER();
        // ---- p3: Q(1,1)   (B'1 slot dead)
        LOAD_A(0, 1);
        STAGE_B(ta, 1, 0);
        BARRIER(); WAIT_LGKM0();
        __builtin_amdgcn_s_setprio(1); MMA_Q(1, 1, bb1); __builtin_amdgcn_s_setprio(0);
        BARRIER();
        // ---- p4: Q(1,0)   (A'1 slot dead); counted wait: tile tb_prev done
        STAGE_A(ta, 1, 0);
        if (i == 15) { WAIT_VM(0); } else { WAIT_VM(8); }
        BARRIER();
        __builtin_amdgcn_s_setprio(1); MMA_Q(1, 0, bb0); __builtin_amdgcn_s_setprio(0);
        BARRIER();
        // ---- p5: Q(0,0) on buf1
        LOAD_A(1, 0);
        LOAD_B(1, 0, bb0);
        BARRIER(); WAIT_LGKM0();
        __builtin_amdgcn_s_setprio(1); MMA_Q(0, 0, bb0); __builtin_amdgcn_s_setprio(0);
        BARRIER();
        // ---- p6: Q(0,1)
        LOAD_B(1, 1, bb1);
        STAGE_A(tb, 0, 32768); STAGE_B(tb, 0, 32768);
        BARRIER(); WAIT_LGKM0();
        __builtin_amdgcn_s_setprio(1); MMA_Q(0, 1, bb1); __builtin_amdgcn_s_setprio(0);
        BARRIER();
        // ---- p7: Q(1,1)
        LOAD_A(1, 1);
        STAGE_B(tb, 1, 32768);
        BARRIER(); WAIT_LGKM0();
        __builtin_amdgcn_s_setprio(1); MMA_Q(1, 1, bb1); __builtin_amdgcn_s_setprio(0);
        BARRIER();
        // ---- p8: Q(1,0); counted wait: tile ta done before next p1
        STAGE_A(tb, 1, 32768);
        if (i < 15) { WAIT_VM(8); }
        BARRIER();
        __builtin_amdgcn_s_setprio(1); MMA_Q(1, 0, bb0); __builtin_amdgcn_s_setprio(0);
        BARRIER();
    }

    // ---- epilogue: two 128-col halves, each one type of one head ----
    const int b = row0 >> 11;
    const int t0g = row0 & 2047;
    #pragma unroll
    for (int ch = 0; ch < 2; ++ch) {
        const int cidx = (col0 >> 7) + ch;       // global 128-col index
        const int head = cidx / 3, type = cidx % 3;   // 0=q 1=k 2=v
        __syncthreads();                         // prev readers done / drain
        if ((wc >> 1) == ch) {                   // waves owning these cols
            #pragma unroll
            for (int ni = 0; ni < 4; ++ni) {
                int d = (wc & 1)*64 + ni*16 + lane15;
                float bv = bias[col0 + ch*128 + d];
                #pragma unroll
                for (int mi = 0; mi < 8; ++mi) {
                    int rowb = wr*128 + mi*16 + quad*4;
                    #pragma unroll
                    for (int r = 0; r < 4; ++r)
                        sm[(rowb + r)*136 + d] = f2bf(acc[mi][ni][r] + bv);
                }
            }
        }
        __syncthreads();
        if (type < 2) {   // q or k: rope + frag store (256 rows x 128 cols)
            const float sc = (type == 0) ? 0.022097086912079608f : 1.0f;
            short* dst = (type == 0 ? qfrag : kfrag) + (size_t)(b*NHEAD + head)*262144;
            #pragma unroll
            for (int it = 0; it < 4; ++it) {
                int c = it*512 + tid;
                int l15 = c & 15, q_ = (c >> 4) & 3, kc = (c >> 6) & 1, rowhi = c >> 7;
                int lrow = rowhi*16 + l15;
                int t = t0g + lrow;
                bf16x8 a8 = *(const bf16x8*)(sm + lrow*136 + kc*32 + q_*8);
                bf16x8 b8 = *(const bf16x8*)(sm + lrow*136 + kc*32 + q_*8 + 64);
                bf16x8 oa, ob;
                if (trig) {
                    const float2* tg = trig + (size_t)(kc*32 + q_*8)*2048 + t;
                    #pragma unroll
                    for (int j = 0; j < 8; ++j) {
                        float2 cs2 = tg[(size_t)j*2048];
                        float va = bf2f(a8[j]), vb = bf2f(b8[j]);
                        oa[j] = f2bf((va*cs2.x - vb*cs2.y)*sc);
                        ob[j] = f2bf((va*cs2.y + vb*cs2.x)*sc);
                    }
                } else {
                    #pragma unroll
                    for (int j = 0; j < 8; ++j) {
                        int d = kc*32 + q_*8 + j;
                        float trev = exp2f(-(float)d * (13.287712379549449f / 64.0f))
                                     * 0.15915494309189535f;
                        float ang = (float)t * trev;
                        float fr = ang - floorf(ang);
                        float sn, cs;
                        __sincosf(fr * 6.283185307179586f, &sn, &cs);
                        float va = bf2f(a8[j]), vb = bf2f(b8[j]);
                        oa[j] = f2bf((va*cs - vb*sn)*sc);
                        ob[j] = f2bf((va*sn + vb*cs)*sc);
                    }
                }
                size_t base = (size_t)((t0g >> 4) + rowhi)*2048 + (q_*16 + l15)*8;
                *(bf16x8*)(dst + base + kc*512)        = oa;
                *(bf16x8*)(dst + base + kc*512 + 1024) = ob;
            }
        } else {          // v: transpose to vfrag (256 rows)
            short* dst = vfrag + (size_t)(b*NHEAD + head)*262144;
            #pragma unroll
            for (int it = 0; it < 8; ++it) {
                int c = it*512 + tid;
                int lane_ = c & 63, rest = c >> 6;
                int q_ = lane_ >> 4, l15 = lane_ & 15;
                int dt = rest & 7, kc2 = (rest >> 3) & 1, kbt = rest >> 4;
                int d = dt*16 + l15;
                bf16x8 v;
                #pragma unroll
                for (int j = 0; j < 8; ++j)
                    v[j] = sm[(kbt*64 + kc2*32 + q_*8 + j)*136 + d];
                *(bf16x8*)(dst + (size_t)((t0g >> 6) + kbt)*8192
                            + dt*1024 + kc2*512 + lane_*8) = v;
            }
        }
    }
}

// ---------------------------------------------------------------------------
// bf16 MFMA GEMM (NT) for out-projection (unchanged, fp32 out).
// ---------------------------------------------------------------------------
__global__ __launch_bounds__(256)
void gemm_out(const short* __restrict__ A, const short* __restrict__ W,
              const float* __restrict__ bias, float* __restrict__ Cout,
              int N, int K)
{
    __shared__ short As[128 * 64];
    __shared__ short Bs[128 * 64];
    const int tid = threadIdx.x;
    const int lane = tid & 63, w = tid >> 6;
    const int lane15 = lane & 15, quad = lane >> 4;
    const int wr = w >> 1, wc = w & 1;
    const int row0 = blockIdx.y * 128, col0 = blockIdx.x * 128;

    f32x4 acc[4][4];
    #pragma unroll
    for (int mi = 0; mi < 4; ++mi)
        #pragma unroll
        for (int ni = 0; ni < 4; ++ni)
            acc[mi][ni] = (f32x4){0.f, 0.f, 0.f, 0.f};

    for (int kt = 0; kt < K; kt += 64) {
        __syncthreads();
        #pragma unroll
        for (int i = 0; i < 4; ++i) {
            int ci = i * 256 + tid;
            int row = ci >> 3, lc = ci & 7;
            int gc = lc ^ (row & 7);
            gload_lds16(A + (size_t)(row0 + row) * K + kt + gc * 8, As + ci * 8);
            gload_lds16(W + (size_t)(col0 + row) * K + kt + gc * 8, Bs + ci * 8);
        }
        __syncthreads();
        #pragma unroll
        for (int kc = 0; kc < 2; ++kc) {
            bf16x8 af[4], bfr[4];
            #pragma unroll
            for (int mi = 0; mi < 4; ++mi) {
                int r = wr * 64 + mi * 16 + lane15;
                af[mi] = *(const bf16x8*)(As + r * 64 + ((kc * 4 + quad) ^ (r & 7)) * 8);
            }
            #pragma unroll
            for (int ni = 0; ni < 4; ++ni) {
                int r = wc * 64 + ni * 16 + lane15;
                bfr[ni] = *(const bf16x8*)(Bs + r * 64 + ((kc * 4 + quad) ^ (r & 7)) * 8);
            }
            #pragma unroll
            for (int mi = 0; mi < 4; ++mi)
                #pragma unroll
                for (int ni = 0; ni < 4; ++ni)
                    acc[mi][ni] = __builtin_amdgcn_mfma_f32_16x16x32_bf16(
                        af[mi], bfr[ni], acc[mi][ni], 0, 0, 0);
        }
    }

    #pragma unroll
    for (int mi = 0; mi < 4; ++mi)
        #pragma unroll
        for (int ni = 0; ni < 4; ++ni) {
            int col = col0 + wc * 64 + ni * 16 + lane15;
            float bv = bias[col];
            #pragma unroll
            for (int r = 0; r < 4; ++r) {
                int row = row0 + wr * 64 + mi * 16 + quad * 4 + r;
                Cout[(size_t)row * N + col] = acc[mi][ni][r] + bv;
            }
        }
}

// ---------------------------------------------------------------------------
// Flash attention (S^T form) with double-buffered K/V staging (round-1
// verified version: barrier -> issue DMA(kb+1 -> buf^1) -> compute(buf)).
// ---------------------------------------------------------------------------
__global__ __launch_bounds__(256)
void attn3(const short* __restrict__ qfrag, const short* __restrict__ kfrag,
           const short* __restrict__ vfrag, short* __restrict__ attnb)
{
    __shared__ short KV[2][16384];        // per buf: K 8192 | V 8192 shorts
    __shared__ short Pb[4][1152];         // per wave: 16 q x stride 72
    const int tid = threadIdx.x;
    const int lane = tid & 63, w = tid >> 6;
    const int lane15 = lane & 15, quad = lane >> 4;
    const int g = (blockIdx.x + blockIdx.y) & 15;
    const int qb = blockIdx.z ? (15 - g) : g;
    const int h = blockIdx.y, b = blockIdx.z;
    const int bh = b * NHEAD + h;
    const int q0 = qb * 128;
    short* Pw = Pb[w];

    bf16x8 qf[2][4];
    {
        const short* qp = qfrag + (size_t)bh * 262144
                        + (size_t)(qb * 8 + w * 2) * 2048 + lane * 8;
        #pragma unroll
        for (int nq = 0; nq < 2; ++nq)
            #pragma unroll
            for (int kc = 0; kc < 4; ++kc)
                qf[nq][kc] = *(const bf16x8*)(qp + nq * 2048 + kc * 512);
    }

    f32x4 acc[8][2];
    #pragma unroll
    for (int dt = 0; dt < 8; ++dt)
        #pragma unroll
        for (int nq = 0; nq < 2; ++nq)
            acc[dt][nq] = (f32x4){0.f, 0.f, 0.f, 0.f};
    float m_s[2] = {-3e38f, -3e38f}, l_s[2] = {0.f, 0.f};

    const short* kf_src = kfrag + (size_t)bh * 262144;
    const short* vf_src = vfrag + (size_t)bh * 262144;
    const int kb_max = 2 * qb + 1;
    const int qtop = q0 + w * 32 + 31;           // wave's largest q index
    const int diag0 = (q0 + w * 32) >> 6;

    // prologue DMA for kb=0
    #pragma unroll
    for (int i = 0; i < 4; ++i) {
        int ci = i * 256 + tid;
        gload_lds16(kf_src + ci * 8, KV[0] + ci * 8);
        gload_lds16(vf_src + ci * 8, KV[0] + 8192 + ci * 8);
    }

    for (int kb = 0; kb <= kb_max; ++kb) {
        __syncthreads();                           // drains buf[kb&1] DMA
        if (kb < kb_max) {                         // prefetch next tile
            const short* ks = kf_src + (size_t)(kb + 1) * 8192;
            const short* vs = vf_src + (size_t)(kb + 1) * 8192;
            short* kd = KV[(kb + 1) & 1];
            #pragma unroll
            for (int i = 0; i < 4; ++i) {
                int ci = i * 256 + tid;
                gload_lds16(ks + ci * 8, kd + ci * 8);
                gload_lds16(vs + ci * 8, kd + 8192 + ci * 8);
            }
        }
        if (kb * 64 > qtop) continue;              // fully masked for this wave
        const short* Ks = KV[kb & 1];
        const short* Vs = Ks + 8192;

        // S^T = K Q^T
        f32x4 st[2][4];
        #pragma unroll
        for (int nq = 0; nq < 2; ++nq)
            #pragma unroll
            for (int mi = 0; mi < 4; ++mi)
                st[nq][mi] = (f32x4){0.f, 0.f, 0.f, 0.f};
        #pragma unroll
        for (int mi = 0; mi < 4; ++mi) {
            bf16x8 kf4[4];
            #pragma unroll
            for (int kc = 0; kc < 4; ++kc)
                kf4[kc] = *(const bf16x8*)(Ks + ((mi * 4 + kc) * 64 + lane) * 8);
            #pragma unroll
            for (int kc = 0; kc < 4; ++kc)
                #pragma unroll
                for (int nq = 0; nq < 2; ++nq)
                    st[nq][mi] = __builtin_amdgcn_mfma_f32_16x16x32_bf16(
                        kf4[kc], qf[nq][kc], st[nq][mi], 0, 0, 0);
        }

        if (kb >= diag0) {
            #pragma unroll
            for (int nq = 0; nq < 2; ++nq) {
                int qg = q0 + w * 32 + nq * 16 + lane15;
                #pragma unroll
                for (int mi = 0; mi < 4; ++mi)
                    #pragma unroll
                    for (int r = 0; r < 4; ++r)
                        if (kb * 64 + mi * 16 + quad * 4 + r > qg)
                            st[nq][mi][r] = -3e38f;
            }
        }

        // softmax + P->LDS (halved buffer, reused across the two nq halves)
        bf16x8 pb[2][2];
        #pragma unroll
        for (int nq = 0; nq < 2; ++nq) {
            float mt = st[nq][0][0];
            #pragma unroll
            for (int mi = 0; mi < 4; ++mi)
                #pragma unroll
                for (int r = 0; r < 4; ++r)
                    mt = fmaxf(mt, st[nq][mi][r]);
            mt = fmaxf(mt, __shfl_xor(mt, 16));
            mt = fmaxf(mt, __shfl_xor(mt, 32));
            float mn = fmaxf(m_s[nq], mt);
            float alpha = __expf(m_s[nq] - mn);
            m_s[nq] = mn;
            float sum = 0.f;
            #pragma unroll
            for (int mi = 0; mi < 4; ++mi)
                #pragma unroll
                for (int r = 0; r < 4; ++r) {
                    float p = __expf(st[nq][mi][r] - mn);
                    st[nq][mi][r] = p;
                    sum += p;
                }
            sum += __shfl_xor(sum, 16);
            sum += __shfl_xor(sum, 32);
            l_s[nq] = l_s[nq] * alpha + sum;
            #pragma unroll
            for (int dt = 0; dt < 8; ++dt) {
                acc[dt][nq][0] *= alpha; acc[dt][nq][1] *= alpha;
                acc[dt][nq][2] *= alpha; acc[dt][nq][3] *= alpha;
            }
            short* pr = Pw + lane15 * 72 + quad * 4;
            #pragma unroll
            for (int mi = 0; mi < 4; ++mi) {
                unsigned lo = (unsigned)(unsigned short)f2bf(st[nq][mi][0])
                            | ((unsigned)(unsigned short)f2bf(st[nq][mi][1]) << 16);
                unsigned hi = (unsigned)(unsigned short)f2bf(st[nq][mi][2])
                            | ((unsigned)(unsigned short)f2bf(st[nq][mi][3]) << 16);
                *(unsigned*)(pr + mi * 16)     = lo;
                *(unsigned*)(pr + mi * 16 + 2) = hi;
            }
            __asm__ volatile("s_waitcnt lgkmcnt(0)" ::: "memory");
            #pragma unroll
            for (int kc2 = 0; kc2 < 2; ++kc2)
                pb[nq][kc2] = *(const bf16x8*)(Pw + lane15 * 72 + kc2 * 32 + quad * 8);
            __asm__ volatile("s_waitcnt lgkmcnt(0)" ::: "memory");  // reads done before nq=1 overwrite
        }

        // O^T += V^T P^T  (each V fragment feeds both nq)
        #pragma unroll
        for (int dt = 0; dt < 8; ++dt)
            #pragma unroll
            for (int kc2 = 0; kc2 < 2; ++kc2) {
                bf16x8 vf = *(const bf16x8*)(Vs + ((dt * 2 + kc2) * 64 + lane) * 8);
                #pragma unroll
                for (int nq = 0; nq < 2; ++nq)
                    acc[dt][nq] = __builtin_amdgcn_mfma_f32_16x16x32_bf16(
                        vf, pb[nq][kc2], acc[dt][nq], 0, 0, 0);
            }
    }

    // epilogue: O^T/l -> LDS transpose -> coalesced bf16 store
    __syncthreads();
    short* Eb = KV[0];                    // 128 x 136
    #pragma unroll
    for (int nq = 0; nq < 2; ++nq) {
        float inv = 1.f / l_s[nq];
        int qrow = w * 32 + nq * 16 + lane15;
        #pragma unroll
        for (int dt = 0; dt < 8; ++dt) {
            unsigned lo = (unsigned)(unsigned short)f2bf(acc[dt][nq][0] * inv)
                        | ((unsigned)(unsigned short)f2bf(acc[dt][nq][1] * inv) << 16);
            unsigned hi = (unsigned)(unsigned short)f2bf(acc[dt][nq][2] * inv)
                        | ((unsigned)(unsigned short)f2bf(acc[dt][nq][3] * inv) << 16);
            *(unsigned*)(Eb + qrow * 136 + dt * 16 + quad * 4)     = lo;
            *(unsigned*)(Eb + qrow * 136 + dt * 16 + quad * 4 + 2) = hi;
        }
    }
    __syncthreads();
    {
        int r = tid >> 1, half = tid & 1;
        short* orow = attnb + (size_t)(b * TSEQ + q0 + r) * DM + h * 128 + half * 64;
        #pragma unroll
        for (int i = 0; i < 8; ++i)
            *(bf16x8*)(orow + i * 8) =
                *(const bf16x8*)(Eb + r * 136 + half * 64 + i * 8);
    }
}

// ---------------------------------------------------------------------------
extern "C" void kernel_launch(void* const* d_in, const int* in_sizes, int n_in,
                              void* d_out, int out_size, void* d_ws, size_t ws_size,
                              hipStream_t stream)
{
    const float* x     = (const float*)d_in[0];
    const float* w_qkv = (const float*)d_in[1];
    const float* b_qkv = (const float*)d_in[2];
    const float* w_out = (const float*)d_in[3];
    const float* b_out = (const float*)d_in[4];
    float* out = (float*)d_out;

    char* ws = (char*)d_ws;
    short* xb    = (short*)(ws);                 // 16.78 MB (reused as attnb)
    short* wqkvb = (short*)(ws + 16777216);      // 25.17 MB
    short* woutb = (short*)(ws + 41943040);      //  8.39 MB
    short* qfrag = (short*)(ws + 50331648);      // 16.78 MB
    short* kfrag = (short*)(ws + 67108864);      // 16.78 MB
    short* vfrag = (short*)(ws + 83886080);      // 16.78 MB  (total 100663296 B)
    short* attnb = xb;                           // x dead after QKV GEMM
    // RoPE trig table (1 MB) after the frag buffers, only if workspace allows
    float2* trig = (ws_size >= 100663296ull + 1048576ull)
                 ? (float2*)(ws + 100663296) : nullptr;

    {   // casts (+ trig table fill if available)
        int grid = trig ? 12800 : 12288;
        cast_all<<<grid, 256, 0, stream>>>(x, xb, w_qkv, wqkvb, w_out, woutb, trig);
    }
    {   // qkv GEMM + bias + rope + fragment repack (256^2 8-phase, hoisted addr)
        dim3 g2(24, 16);
        gemm_qkv_rope<<<g2, 512, 0, stream>>>(xb, wqkvb, b_qkv, qfrag, kfrag, vfrag, trig);
    }
    {   // flash attention
        dim3 g2(16, NHEAD, BATCH);
        attn3<<<g2, 256, 0, stream>>>(qfrag, kfrag, vfrag, attnb);
    }
    {   // out = attn @ w_out^T + b_out
        dim3 g2(16, 32);
        gemm_out<<<g2, 256, 0, stream>>>(attnb, woutb, b_out, out, 2048, 2048);
    }
}